// Round 4
// baseline (1564.027 us; speedup 1.0000x reference)
//
#include <hip/hip_runtime.h>
#include <math.h>

#define BB 64
#define NN 4096
#define FF 128
#define KK 64
#define TILE 128
#define NSTEP 4
#define SPB 32
#define NTB 8      // tile-blocks per batch (partial slots)

typedef short bf16x8 __attribute__((ext_vector_type(8)));
typedef float f32x4 __attribute__((ext_vector_type(4)));

__device__ __forceinline__ ushort f2bf(float f) {
    union { float f; unsigned u; } c; c.f = f;
    unsigned r = c.u + 0x7FFFu + ((c.u >> 16) & 1u);
    return (ushort)(r >> 16);
}
__device__ __forceinline__ float bf2f(ushort h) {
    union { unsigned u; float f; } c; c.u = ((unsigned)h) << 16;
    return c.f;
}

// ---------- stats: partial sums of emb and emb^2 over n (masked) ----------
__global__ void k_stats_part(const float* __restrict__ emb, const int* __restrict__ nbv,
                             float* __restrict__ spart) {
    int b = blockIdx.y, s = blockIdx.x;
    int nb = nbv[b];
    int t = threadIdx.x;                 // 256
    int c = t & 31, rr = t >> 5;
    int n0 = s * (NN / SPB);
    int n1 = min(n0 + NN / SPB, nb);
    float4 s1 = {0,0,0,0}, s2 = {0,0,0,0};
    const float4* base = (const float4*)(emb + (size_t)b * NN * FF);
    for (int n = n0 + rr; n < n1; n += 8) {
        float4 e = base[(size_t)n * 32 + c];
        s1.x += e.x; s1.y += e.y; s1.z += e.z; s1.w += e.w;
        s2.x += e.x*e.x; s2.y += e.y*e.y; s2.z += e.z*e.z; s2.w += e.w*e.w;
    }
    __shared__ __align__(16) float4 r1[8][32];
    __shared__ __align__(16) float4 r2[8][32];
    r1[rr][c] = s1; r2[rr][c] = s2;
    __syncthreads();
    if (t < 32) {
        float4 a1 = r1[0][t], a2 = r2[0][t];
        #pragma unroll
        for (int r = 1; r < 8; ++r) {
            float4 u = r1[r][t], v = r2[r][t];
            a1.x+=u.x; a1.y+=u.y; a1.z+=u.z; a1.w+=u.w;
            a2.x+=v.x; a2.y+=v.y; a2.z+=v.z; a2.w+=v.w;
        }
        ((float4*)(spart + ((size_t)(b*SPB+s)*2 + 0)*FF))[t] = a1;
        ((float4*)(spart + ((size_t)(b*SPB+s)*2 + 1)*FF))[t] = a2;
    }
}

// ---------- stats finalize ----------
__global__ void k_stats_fin(const float* __restrict__ spart, const int* __restrict__ nbv,
                            float* __restrict__ meanp, float* __restrict__ rstdp) {
    int b = blockIdx.x, f = threadIdx.x;   // 128 threads
    float s1 = 0.f, s2 = 0.f;
    for (int s = 0; s < SPB; ++s) {
        s1 += spart[((size_t)(b*SPB+s)*2 + 0)*FF + f];
        s2 += spart[((size_t)(b*SPB+s)*2 + 1)*FF + f];
    }
    float nb = (float)nbv[b];
    float mean = s1 / nb;
    float var = s2 / nb - mean * mean;
    meanp[b*FF + f] = mean;
    rstdp[b*FF + f] = rsqrtf(var + 1e-5f);
}

// ---------- init mu = x[:, init_idx] (f32) ----------
__global__ void k_init(const float* __restrict__ emb, const int* __restrict__ nbv,
                       const int* __restrict__ init_idx,
                       const float* __restrict__ meanp, const float* __restrict__ rstdp,
                       float* __restrict__ mu) {
    size_t i = (size_t)blockIdx.x * 256 + threadIdx.x;   // < B*K*F
    int f = (int)(i & 127);
    int k = (int)((i >> 7) & 63);
    int b = (int)(i >> 13);
    int row = init_idx[k];
    float v = 0.f;
    if (row < nbv[b]) {
        float e = emb[((size_t)b * NN + row) * FF + f];
        v = (e - meanp[b*FF + f]) * rstdp[b*FF + f];
    }
    mu[i] = v;
}

// ---------- split mu f32 -> bf16 hi/lo + |mu|^2 (used once, after k_init) ----------
__global__ void k_split(const float* __restrict__ mu, ushort* __restrict__ muh,
                        ushort* __restrict__ mul, float* __restrict__ m2g) {
    int b = blockIdx.x, t = threadIdx.x;   // 256 threads
    int k = t >> 2, q = t & 3;
    size_t base = ((size_t)b * KK + k) * FF + q * 32;
    float m2 = 0.f;
    #pragma unroll
    for (int it = 0; it < 8; ++it) {
        float4 v = *(const float4*)(mu + base + it*4);
        m2 += v.x*v.x + v.y*v.y + v.z*v.z + v.w*v.w;
        ushort4 h4, l4;
        h4.x = f2bf(v.x); l4.x = f2bf(v.x - bf2f(h4.x));
        h4.y = f2bf(v.y); l4.y = f2bf(v.y - bf2f(h4.y));
        h4.z = f2bf(v.z); l4.z = f2bf(v.z - bf2f(h4.z));
        h4.w = f2bf(v.w); l4.w = f2bf(v.w - bf2f(h4.w));
        *(ushort4*)(muh + base + it*4) = h4;
        *(ushort4*)(mul + base + it*4) = l4;
    }
    m2 += __shfl_xor(m2, 1); m2 += __shfl_xor(m2, 2);
    if (q == 0) m2g[b*KK + k] = m2;
}

// ---------- EM step: MFMA split-bf16, NTB blocks/batch, 4-tile strided loop ----------
__global__ __launch_bounds__(1024, 8) void k_em4(const float* __restrict__ emb,
                                                 const int* __restrict__ nbv,
                                                 const float* __restrict__ meanp,
                                                 const float* __restrict__ rstdp,
                                                 const ushort* __restrict__ muh,
                                                 const ushort* __restrict__ mul,
                                                 const float* __restrict__ m2g,
                                                 float* __restrict__ partial) {
    __shared__ __align__(16) ushort xTh[FF * 64];   // 16 KB  [f][64 n-half], granule^=(f&7)
    __shared__ __align__(16) ushort xTl[FF * 64];   // 16 KB
    __shared__ __align__(16) ushort pTh[KK * TILE]; // 16 KB  [k][128 n], granule^=(k&7)
    __shared__ __align__(16) ushort pTl[KK * TILE]; // 16 KB

    int bb = blockIdx.y, t0 = blockIdx.x;           // t0 in [0, NTB)
    int nb = nbv[bb];
    int t = threadIdx.x;                  // 1024
    int lane = t & 63, w = t >> 6;        // 16 waves
    int b = lane & 15, g = lane >> 4;

    const float* mnB = meanp + bb * FF;
    const float* rsB = rstdp + bb * FF;

    // persistent GEMM2 accumulators (chain across tiles)
    int mt2 = w & 3;
    int fpair = w >> 2;
    int kA = 16*mt2 + b;
    int fB0 = 16*(2*fpair) + b;
    int fB1 = 16*(2*fpair + 1) + b;
    f32x4 c0 = {0.f,0.f,0.f,0.f}, c1 = {0.f,0.f,0.f,0.f};

    #pragma unroll 1
    for (int it = 0; it < 4; ++it) {
        int tt = t0 + NTB * it;           // strided tiles: per-batch imbalance <= 1 iter
        int row0 = tt * TILE;
        if (row0 >= nb) break;            // uniform across block

        f32x4 acc1[4];
        float a2 = 0.f;

        if (w < 8) {
            // ===== GEMM1: S = x . mu^T ; A on-the-fly from emb, B from global mu =====
            #pragma unroll
            for (int kt = 0; kt < 4; ++kt) acc1[kt] = (f32x4){0.f,0.f,0.f,0.f};
            int nA = row0 + 16*w + b;
            const float* erow = emb + ((size_t)bb * NN + nA) * FF;
            const ushort* muhB = muh + (size_t)bb * KK * FF;
            const ushort* mulB = mul + (size_t)bb * KK * FF;
            #pragma unroll
            for (int kk = 0; kk < 4; ++kk) {
                int f0 = kk*32 + g*8;
                float4 e0 = *(const float4*)(erow + f0);
                float4 e1 = *(const float4*)(erow + f0 + 4);
                float4 m0 = *(const float4*)(mnB + f0);
                float4 m1 = *(const float4*)(mnB + f0 + 4);
                float4 r0 = *(const float4*)(rsB + f0);
                float4 r1 = *(const float4*)(rsB + f0 + 4);
                float vv[8];
                vv[0] = (e0.x - m0.x)*r0.x; vv[1] = (e0.y - m0.y)*r0.y;
                vv[2] = (e0.z - m0.z)*r0.z; vv[3] = (e0.w - m0.w)*r0.w;
                vv[4] = (e1.x - m1.x)*r1.x; vv[5] = (e1.y - m1.y)*r1.y;
                vv[6] = (e1.z - m1.z)*r1.z; vv[7] = (e1.w - m1.w)*r1.w;
                bf16x8 ah, al;
                #pragma unroll
                for (int i = 0; i < 8; ++i) {
                    a2 += vv[i]*vv[i];
                    ushort h = f2bf(vv[i]);
                    ah[i] = (short)h;
                    al[i] = (short)f2bf(vv[i] - bf2f(h));
                }
                #pragma unroll
                for (int kt = 0; kt < 4; ++kt) {
                    size_t mo = (size_t)(kt*16 + b) * FF + f0;
                    bf16x8 Bh = *(const bf16x8*)(muhB + mo);
                    bf16x8 Bl = *(const bf16x8*)(mulB + mo);
                    acc1[kt] = __builtin_amdgcn_mfma_f32_16x16x32_bf16(ah, Bh, acc1[kt], 0, 0, 0);
                    acc1[kt] = __builtin_amdgcn_mfma_f32_16x16x32_bf16(ah, Bl, acc1[kt], 0, 0, 0);
                    acc1[kt] = __builtin_amdgcn_mfma_f32_16x16x32_bf16(al, Bh, acc1[kt], 0, 0, 0);
                }
            }
            a2 += __shfl_xor(a2, 16);
            a2 += __shfl_xor(a2, 32);
        } else {
            // ===== build xT half 1 (tile rows 0..63) =====
            int t2 = t - 512;
            int nl = t2 & 63;
            int fq = t2 >> 6;
            int gn = row0 + nl;
            bool valid = gn < nb;
            const float* er = emb + ((size_t)bb * NN + gn) * FF;
            #pragma unroll
            for (int itr = 0; itr < 4; ++itr) {
                int f4 = fq + 8*itr;
                float4 e = valid ? *(const float4*)(er + 4*f4) : make_float4(0.f,0.f,0.f,0.f);
                float4 mn = *(const float4*)(mnB + 4*f4);
                float4 rs = *(const float4*)(rsB + 4*f4);
                float vx[4];
                vx[0] = valid ? (e.x - mn.x)*rs.x : 0.f;
                vx[1] = valid ? (e.y - mn.y)*rs.y : 0.f;
                vx[2] = valid ? (e.z - mn.z)*rs.z : 0.f;
                vx[3] = valid ? (e.w - mn.w)*rs.w : 0.f;
                #pragma unroll
                for (int ei = 0; ei < 4; ++ei) {
                    int f = 4*f4 + ei;
                    ushort h = f2bf(vx[ei]);
                    ushort l = f2bf(vx[ei] - bf2f(h));
                    int idx = f*64 + ((((nl>>3) ^ (f&7)) << 3) | (nl & 7));
                    xTh[idx] = h;
                    xTl[idx] = l;
                }
            }
        }
        __syncthreads();   // bar1: xT half1 + GEMM1 regs ready

        if (w < 8) {
            // ===== softmax rows -> P (hi/lo) transposed into LDS =====
            float x2v[4], m2v[4];
            #pragma unroll
            for (int j = 0; j < 4; ++j) x2v[j] = __shfl(a2, 4*g + j);
            #pragma unroll
            for (int kt = 0; kt < 4; ++kt) m2v[kt] = m2g[bb*KK + kt*16 + b];
            float lik[4][4];
            float tot[4] = {0.f, 0.f, 0.f, 0.f};
            #pragma unroll
            for (int kt = 0; kt < 4; ++kt)
                #pragma unroll
                for (int j = 0; j < 4; ++j) {
                    float s = acc1[kt][j];
                    float L = expf(-0.5f * (x2v[j] - 2.f*s + m2v[kt])) + 1e-20f;
                    lik[kt][j] = L;
                    tot[j] += L;
                }
            #pragma unroll
            for (int j = 0; j < 4; ++j) {
                tot[j] += __shfl_xor(tot[j], 1);
                tot[j] += __shfl_xor(tot[j], 2);
                tot[j] += __shfl_xor(tot[j], 4);
                tot[j] += __shfl_xor(tot[j], 8);
                tot[j] = 1.f / (tot[j] + 1e-40f);
            }
            int np = 16*w + 4*g;
            #pragma unroll
            for (int kt = 0; kt < 4; ++kt) {
                int k = kt*16 + b;
                ushort4 uh, ul;
                float P0 = lik[kt][0]*tot[0]; uh.x = f2bf(P0); ul.x = f2bf(P0 - bf2f(uh.x));
                float P1 = lik[kt][1]*tot[1]; uh.y = f2bf(P1); ul.y = f2bf(P1 - bf2f(uh.y));
                float P2 = lik[kt][2]*tot[2]; uh.z = f2bf(P2); ul.z = f2bf(P2 - bf2f(uh.z));
                float P3 = lik[kt][3]*tot[3]; uh.w = f2bf(P3); ul.w = f2bf(P3 - bf2f(uh.w));
                int idx = k*TILE + (((np>>3) ^ (k&7)) << 3) + (np & 7);
                *(ushort4*)(&pTh[idx]) = uh;
                *(ushort4*)(&pTl[idx]) = ul;
            }
        }
        __syncthreads();   // bar2: pT ready

        // ===== GEMM2 part 1: n = 0..63 =====
        #pragma unroll
        for (int ns = 0; ns < 2; ++ns) {
            int gp = 4*ns + g;
            int gx = 4*ns + g;
            int ia = kA*TILE + ((gp ^ (kA&7)) << 3);
            bf16x8 Ah = *(const bf16x8*)(&pTh[ia]);
            bf16x8 Al = *(const bf16x8*)(&pTl[ia]);
            int ib0 = fB0*64 + ((gx ^ (fB0&7)) << 3);
            int ib1 = fB1*64 + ((gx ^ (fB1&7)) << 3);
            bf16x8 B0h = *(const bf16x8*)(&xTh[ib0]);
            bf16x8 B0l = *(const bf16x8*)(&xTl[ib0]);
            bf16x8 B1h = *(const bf16x8*)(&xTh[ib1]);
            bf16x8 B1l = *(const bf16x8*)(&xTl[ib1]);
            c0 = __builtin_amdgcn_mfma_f32_16x16x32_bf16(Ah, B0h, c0, 0, 0, 0);
            c0 = __builtin_amdgcn_mfma_f32_16x16x32_bf16(Ah, B0l, c0, 0, 0, 0);
            c0 = __builtin_amdgcn_mfma_f32_16x16x32_bf16(Al, B0h, c0, 0, 0, 0);
            c1 = __builtin_amdgcn_mfma_f32_16x16x32_bf16(Ah, B1h, c1, 0, 0, 0);
            c1 = __builtin_amdgcn_mfma_f32_16x16x32_bf16(Ah, B1l, c1, 0, 0, 0);
            c1 = __builtin_amdgcn_mfma_f32_16x16x32_bf16(Al, B1h, c1, 0, 0, 0);
        }
        __syncthreads();   // bar3: done reading xT half1

        {   // ===== rebuild xT with tile rows 64..127 (all 16 waves) =====
            int nl = t & 63;
            int fq = t >> 6;
            int gn = row0 + 64 + nl;
            bool valid = gn < nb;
            const float* er = emb + ((size_t)bb * NN + gn) * FF;
            #pragma unroll
            for (int itr = 0; itr < 2; ++itr) {
                int f4 = fq + 16*itr;
                float4 e = valid ? *(const float4*)(er + 4*f4) : make_float4(0.f,0.f,0.f,0.f);
                float4 mn = *(const float4*)(mnB + 4*f4);
                float4 rs = *(const float4*)(rsB + 4*f4);
                float vx[4];
                vx[0] = valid ? (e.x - mn.x)*rs.x : 0.f;
                vx[1] = valid ? (e.y - mn.y)*rs.y : 0.f;
                vx[2] = valid ? (e.z - mn.z)*rs.z : 0.f;
                vx[3] = valid ? (e.w - mn.w)*rs.w : 0.f;
                #pragma unroll
                for (int ei = 0; ei < 4; ++ei) {
                    int f = 4*f4 + ei;
                    ushort h = f2bf(vx[ei]);
                    ushort l = f2bf(vx[ei] - bf2f(h));
                    int idx = f*64 + ((((nl>>3) ^ (f&7)) << 3) | (nl & 7));
                    xTh[idx] = h;
                    xTl[idx] = l;
                }
            }
        }
        __syncthreads();   // bar4: xT half2 ready

        // ===== GEMM2 part 2: n = 64..127 =====
        #pragma unroll
        for (int ns = 2; ns < 4; ++ns) {
            int gp = 4*ns + g;
            int gx = 4*(ns - 2) + g;
            int ia = kA*TILE + ((gp ^ (kA&7)) << 3);
            bf16x8 Ah = *(const bf16x8*)(&pTh[ia]);
            bf16x8 Al = *(const bf16x8*)(&pTl[ia]);
            int ib0 = fB0*64 + ((gx ^ (fB0&7)) << 3);
            int ib1 = fB1*64 + ((gx ^ (fB1&7)) << 3);
            bf16x8 B0h = *(const bf16x8*)(&xTh[ib0]);
            bf16x8 B0l = *(const bf16x8*)(&xTl[ib0]);
            bf16x8 B1h = *(const bf16x8*)(&xTh[ib1]);
            bf16x8 B1l = *(const bf16x8*)(&xTl[ib1]);
            c0 = __builtin_amdgcn_mfma_f32_16x16x32_bf16(Ah, B0h, c0, 0, 0, 0);
            c0 = __builtin_amdgcn_mfma_f32_16x16x32_bf16(Ah, B0l, c0, 0, 0, 0);
            c0 = __builtin_amdgcn_mfma_f32_16x16x32_bf16(Al, B0h, c0, 0, 0, 0);
            c1 = __builtin_amdgcn_mfma_f32_16x16x32_bf16(Ah, B1h, c1, 0, 0, 0);
            c1 = __builtin_amdgcn_mfma_f32_16x16x32_bf16(Ah, B1l, c1, 0, 0, 0);
            c1 = __builtin_amdgcn_mfma_f32_16x16x32_bf16(Al, B1h, c1, 0, 0, 0);
        }
        __syncthreads();   // bar5: done reading xT/pT before next tile overwrites
    }

    // ===== epilogue: plain-store partial slot t0 (always written, even if 0 tiles) =====
    {
        float* pp = partial + ((size_t)t0 * BB + bb) * KK * FF;
        #pragma unroll
        for (int j = 0; j < 4; ++j) {
            int ko = 16*mt2 + 4*g + j;
            pp[(size_t)ko * FF + fB0] = c0[j];
            pp[(size_t)ko * FF + fB1] = c1[j];
        }
    }
}

// ---------- reduce NTB partials -> muF, and fused split (muh/mul) + |mu|^2 ----------
__global__ void k_reduce8(const float* __restrict__ partial, float* __restrict__ muF,
                          ushort* __restrict__ muh, ushort* __restrict__ mul,
                          float* __restrict__ m2g) {
    int b = blockIdx.x;           // BB
    int t = threadIdx.x;          // 512
    int w = t >> 6, lane = t & 63;
    #pragma unroll
    for (int i = 0; i < 8; ++i) {
        int k = w * 8 + i;
        size_t off = ((size_t)b * KK + k) * FF + lane * 2;
        float sx = 0.f, sy = 0.f;
        #pragma unroll
        for (int sl = 0; sl < NTB; ++sl) {
            float2 v = *(const float2*)(partial + (size_t)sl * BB * KK * FF + off);
            sx += v.x; sy += v.y;
        }
        *(float2*)(muF + off) = make_float2(sx, sy);
        ushort2 h2, l2;
        h2.x = f2bf(sx); l2.x = f2bf(sx - bf2f(h2.x));
        h2.y = f2bf(sy); l2.y = f2bf(sy - bf2f(h2.y));
        *(ushort2*)(muh + off) = h2;
        *(ushort2*)(mul + off) = l2;
        float q = sx*sx + sy*sy;
        q += __shfl_xor(q, 1); q += __shfl_xor(q, 2); q += __shfl_xor(q, 4);
        q += __shfl_xor(q, 8); q += __shfl_xor(q, 16); q += __shfl_xor(q, 32);
        if (lane == 0) m2g[b * KK + k] = q;
    }
}

// ---------- final: out[b] = sigmoid(mean_k(mu . w) + bias) ----------
__global__ void k_final(const float* __restrict__ mu, const float* __restrict__ fc_w,
                        const float* __restrict__ fc_b, float* __restrict__ out) {
    int b = blockIdx.x, t = threadIdx.x;     // 256 threads
    int k = t >> 2, q = t & 3;
    const float* m = mu + ((size_t)b * KK + k) * FF + q * 32;
    const float* wv = fc_w + q * 32;
    float s = 0.f;
    #pragma unroll
    for (int i = 0; i < 32; ++i) s = fmaf(m[i], wv[i], s);
    s += __shfl_xor(s, 1); s += __shfl_xor(s, 2);
    __shared__ float kd[KK];
    if (q == 0) kd[k] = s;
    __syncthreads();
    if (t < 64) {
        float v = kd[t];
        v += __shfl_xor(v, 1);  v += __shfl_xor(v, 2);  v += __shfl_xor(v, 4);
        v += __shfl_xor(v, 8);  v += __shfl_xor(v, 16); v += __shfl_xor(v, 32);
        if (t == 0) {
            float o = v / (float)KK + fc_b[0];
            out[b] = 1.f / (1.f + expf(-o));
        }
    }
}

extern "C" void kernel_launch(void* const* d_in, const int* in_sizes, int n_in,
                              void* d_out, int out_size, void* d_ws, size_t ws_size,
                              hipStream_t stream) {
    const float* emb      = (const float*)d_in[0];
    // d_in[1] = mask — redundant with batch_nb_nodes; unused
    const float* fc_w     = (const float*)d_in[2];
    const float* fc_b     = (const float*)d_in[3];
    const int*   nbv      = (const int*)d_in[4];
    const int*   init_idx = (const int*)d_in[5];
    float* out = (float*)d_out;

    float* wsf   = (float*)d_ws;
    float* meanp = wsf;                                // B*F
    float* rstdp = meanp + BB*FF;                      // B*F
    float* spart = rstdp + BB*FF;                      // B*SPB*2*F
    float* muF   = spart + (size_t)BB*SPB*2*FF;        // B*K*F f32
    float* m2g   = muF + (size_t)BB*KK*FF;             // B*K
    ushort* muh  = (ushort*)(m2g + BB*KK);             // B*K*F bf16
    ushort* mul  = muh + (size_t)BB*KK*FF;             // B*K*F bf16
    float* part  = (float*)(mul + (size_t)BB*KK*FF);   // NTB*B*K*F f32 (16.8 MB)

    k_stats_part<<<dim3(SPB, BB), 256, 0, stream>>>(emb, nbv, spart);
    k_stats_fin<<<BB, 128, 0, stream>>>(spart, nbv, meanp, rstdp);
    k_init<<<(BB*KK*FF)/256, 256, 0, stream>>>(emb, nbv, init_idx, meanp, rstdp, muF);
    k_split<<<BB, 256, 0, stream>>>(muF, muh, mul, m2g);

    for (int step = 0; step < NSTEP; ++step) {
        k_em4<<<dim3(NTB, BB), 1024, 0, stream>>>(emb, nbv, meanp, rstdp,
                                                  muh, mul, m2g, part);
        k_reduce8<<<BB, 512, 0, stream>>>(part, muF, muh, mul, m2g);
    }
    k_final<<<BB, 256, 0, stream>>>(muF, fc_w, fc_b, out);
}